// Round 1
// baseline (715.087 us; speedup 1.0000x reference)
//
#include <hip/hip_runtime.h>

typedef __bf16 bf16;
typedef __bf16 bf16x4 __attribute__((ext_vector_type(4)));
typedef __bf16 bf16x8 __attribute__((ext_vector_type(8)));
typedef float  fx4    __attribute__((ext_vector_type(4)));

#define MFMA16(a, b, c) __builtin_amdgcn_mfma_f32_16x16x32_bf16((a), (b), (c), 0, 0, 0)

// B=4, N=2048, E=768, H=8, D=96; M = B*N = 8192. User tensors fp32, out fp32.

// ---------------------------------------------------------------------------
// Barrier WITHOUT the vmem drain. __syncthreads() emits
// "s_waitcnt vmcnt(0) lgkmcnt(0); s_barrier" — the vmcnt(0) kills register
// prefetch. LDS cross-wave visibility only needs lgkmcnt(0).
// 0xC07F = vmcnt 63 (no wait), expcnt 7 (no wait), lgkmcnt 0.
// ---------------------------------------------------------------------------
__device__ __forceinline__ void barrier_nodrain() {
  __asm__ __volatile__("" ::: "memory");
  __builtin_amdgcn_s_waitcnt(0xC07F);
  __builtin_amdgcn_s_barrier();
  __asm__ __volatile__("" ::: "memory");
}

// ---------------------------------------------------------------------------
// x (fp32) -> bf16, 4 elems/thread.
// ---------------------------------------------------------------------------
__global__ __launch_bounds__(256)
void cvt_x_kernel(const float* __restrict__ x, bf16* __restrict__ xb) {
  const int i = (blockIdx.x * 256 + threadIdx.x) * 4;
  float4 v = *(const float4*)&x[i];
  bf16x4 o;
  o[0] = (bf16)v.x; o[1] = (bf16)v.y; o[2] = (bf16)v.z; o[3] = (bf16)v.w;
  *(bf16x4*)&xb[i] = o;
}

// ---------------------------------------------------------------------------
// Fused QKV GEMM (round-7 proven, untouched). blockIdx.x: 0-5 Q, 6-11 K,
// 12-17 V (transposed out). 1152 blocks. Tile 128x128, BK=32, 4 waves.
// ---------------------------------------------------------------------------
__global__ __launch_bounds__(256)
void gemm_qkv(const bf16* __restrict__ A,
              const float* __restrict__ Wq, const float* __restrict__ Wk,
              const float* __restrict__ Wv,
              const float* __restrict__ bq, const float* __restrict__ bk,
              const float* __restrict__ bv,
              bf16* __restrict__ Qo, bf16* __restrict__ Ko,
              bf16* __restrict__ Vto) {
  constexpr int K = 768;
  __shared__ __align__(16) bf16 As[128 * 32];
  __shared__ __align__(16) bf16 Bs[128 * 32];

  const int tid  = threadIdx.x;
  const int wave = tid >> 6;
  const int lane = tid & 63;
  const int l15  = lane & 15;
  const int q4   = lane >> 4;
  const int wr   = wave >> 1;
  const int wc   = wave & 1;
  const int sel  = blockIdx.x / 6;
  const int cb0  = (blockIdx.x % 6) * 128;
  const int rb0  = blockIdx.y * 128;

  const float* W   = (sel == 0) ? Wq : (sel == 1) ? Wk : Wv;
  const float* bia = (sel == 0) ? bq : (sel == 1) ? bk : bv;

  fx4 acc[4][4];
#pragma unroll
  for (int i = 0; i < 4; i++)
#pragma unroll
    for (int j = 0; j < 4; j++) acc[i][j] = (fx4){0.f, 0.f, 0.f, 0.f};

  for (int k0 = 0; k0 < K; k0 += 32) {
    for (int c = tid; c < 512; c += 256) {
      const int row = c >> 2;
      const int kc  = (c & 3) << 3;
      *(uint4*)&As[row * 32 + kc] =
          *(const uint4*)&A[(size_t)(rb0 + row) * K + k0 + kc];
      const float* sb = W + (size_t)(cb0 + row) * K + k0 + kc;
      bf16x8 pb;
#pragma unroll
      for (int t = 0; t < 8; t++) pb[t] = (bf16)sb[t];
      *(bf16x8*)&Bs[row * 32 + kc] = pb;
    }
    __syncthreads();

    bf16x8 a[4], b[4];
#pragma unroll
    for (int i = 0; i < 4; i++)
      a[i] = *(const bf16x8*)&As[(wr * 64 + i * 16 + l15) * 32 + q4 * 8];
#pragma unroll
    for (int j = 0; j < 4; j++)
      b[j] = *(const bf16x8*)&Bs[(wc * 64 + j * 16 + l15) * 32 + q4 * 8];
#pragma unroll
    for (int i = 0; i < 4; i++)
#pragma unroll
      for (int j = 0; j < 4; j++)
        acc[i][j] = MFMA16(a[i], b[j], acc[i][j]);
    __syncthreads();
  }

  const int cb = cb0 + wc * 64;
  const int rb = rb0 + wr * 64;
  bf16* Co = (sel == 0) ? Qo : Ko;
#pragma unroll
  for (int j = 0; j < 4; j++) {
    const int o  = cb + j * 16 + l15;
    const float bj = bia[o];
#pragma unroll
    for (int i = 0; i < 4; i++) {
      const int r0 = rb + i * 16 + q4 * 4;
      if (sel == 2) {
        const int bb = r0 >> 11;
        const int n0 = r0 & 2047;
        bf16x4 pk;
#pragma unroll
        for (int r = 0; r < 4; r++) pk[r] = (bf16)(acc[i][j][r] + bj);
        *(bf16x4*)&Vto[((size_t)(bb * 768 + o)) * 2048 + n0] = pk;
      } else {
#pragma unroll
        for (int r = 0; r < 4; r++)
          Co[(size_t)(r0 + r) * 768 + o] = (bf16)(acc[i][j][r] + bj);
      }
    }
  }
}

// ---------------------------------------------------------------------------
// Output projection: out[M,768] fp32 = AO bf16 @ Wo^T + bo (untouched).
// ---------------------------------------------------------------------------
__global__ __launch_bounds__(256)
void gemm_o(const bf16* __restrict__ A, const float* __restrict__ W,
            const float* __restrict__ bias, float* __restrict__ C) {
  constexpr int K = 768;
  __shared__ __align__(16) bf16 As[128 * 32];
  __shared__ __align__(16) bf16 Bs[128 * 32];

  const int tid  = threadIdx.x;
  const int wave = tid >> 6;
  const int lane = tid & 63;
  const int l15  = lane & 15;
  const int q4   = lane >> 4;
  const int wr   = wave >> 1;
  const int wc   = wave & 1;
  const int rb0  = blockIdx.y * 128;
  const int cb0  = blockIdx.x * 128;

  fx4 acc[4][4];
#pragma unroll
  for (int i = 0; i < 4; i++)
#pragma unroll
    for (int j = 0; j < 4; j++) acc[i][j] = (fx4){0.f, 0.f, 0.f, 0.f};

  for (int k0 = 0; k0 < K; k0 += 32) {
    for (int c = tid; c < 512; c += 256) {
      const int row = c >> 2;
      const int kc  = (c & 3) << 3;
      *(uint4*)&As[row * 32 + kc] =
          *(const uint4*)&A[(size_t)(rb0 + row) * K + k0 + kc];
      const float* sb = W + (size_t)(cb0 + row) * K + k0 + kc;
      bf16x8 pb;
#pragma unroll
      for (int t = 0; t < 8; t++) pb[t] = (bf16)sb[t];
      *(bf16x8*)&Bs[row * 32 + kc] = pb;
    }
    __syncthreads();

    bf16x8 a[4], b[4];
#pragma unroll
    for (int i = 0; i < 4; i++)
      a[i] = *(const bf16x8*)&As[(wr * 64 + i * 16 + l15) * 32 + q4 * 8];
#pragma unroll
    for (int j = 0; j < 4; j++)
      b[j] = *(const bf16x8*)&Bs[(wc * 64 + j * 16 + l15) * 32 + q4 * 8];
#pragma unroll
    for (int i = 0; i < 4; i++)
#pragma unroll
      for (int j = 0; j < 4; j++)
        acc[i][j] = MFMA16(a[i], b[j], acc[i][j]);
    __syncthreads();
  }

  const int cb = cb0 + wc * 64;
  const int rb = rb0 + wr * 64;
#pragma unroll
  for (int j = 0; j < 4; j++) {
    const int o  = cb + j * 16 + l15;
    const float bj = bias[o];
#pragma unroll
    for (int i = 0; i < 4; i++) {
      const int r0 = rb + i * 16 + q4 * 4;
#pragma unroll
      for (int r = 0; r < 4; r++)
        C[(size_t)(r0 + r) * 768 + o] = acc[i][j][r] + bj;
    }
  }
}

// ---------------------------------------------------------------------------
// Attention, softmax over HEADS (dim=1), / sqrt(768).
// R11: q-tile split 32 -> 16 rows. Softmax-over-heads makes every k column
// independent, so the q split is algorithmically free. Grid 256 -> 512 blocks
// = 2 blocks/CU (was exactly 1 block/CU -> 22.6% occupancy, MfmaUtil 10%,
// VALUBusy 20% — pure latency-bound: the lone block's 8 waves march in
// lockstep through barrier -> serial exp-chain -> barrier with nothing else
// on the CU to fill the stalls). Two independent blocks interleave phases.
// Per-wave live state shrinks ~48 VGPRs (aq 6->3 frags, o 12->6, e 4->2),
// so __launch_bounds__(512,4) (VGPR cap 128, 4 waves/SIMD) should hold
// without spills. LDS 49.7 KB -> 24.7 KB.
// Structure otherwise identical: register double-buffered K/V prefetch,
// nodrain barriers, Ebuf q-stride 260 (2-way scatter: free), AO aliases Q
// (block reads only its own 16 Q rows before the loop, writes only those
// rows after it — disjoint across blocks).
// ---------------------------------------------------------------------------
__global__ __launch_bounds__(512, 4)
void attn_kernel(const bf16* Q, const bf16* __restrict__ Kb,
                 const bf16* __restrict__ Vt, bf16* AO) {
  __shared__ __align__(16) float Ebuf[16 * 260];     // [q][h*32+k], 16.6 KB
  __shared__ __align__(16) bf16  Pbuf[8 * 16 * 32];  // [h][q][k],    8 KB

  const int tid  = threadIdx.x;
  const int h    = tid >> 6;
  const int lane = tid & 63;
  const int l15  = lane & 15;
  const int q4   = lane >> 4;
  const int b    = blockIdx.x >> 7;
  const int qt   = blockIdx.x & 127;
  const int qrow0 = b * 2048 + qt * 16;

  // Persistent Q fragments: 1 q-16tile x 3 d-chunks.
  bf16x8 aq[3];
#pragma unroll
  for (int c = 0; c < 3; c++)
    aq[c] = *(const bf16x8*)
        &Q[(size_t)(qrow0 + l15) * 768 + h * 96 + c * 32 + q4 * 8];

  fx4 o[6];
#pragma unroll
  for (int j = 0; j < 6; j++) o[j] = (fx4){0.f, 0.f, 0.f, 0.f};

  // Per-lane fixed base pointers.
  const bf16* Kp0 = Kb + (size_t)(b * 2048 + l15) * 768 + h * 96 + q4 * 8;
  const bf16* Vp0 = Vt + (size_t)((b * 8 + h) * 96 + l15) * 2048 + q4 * 8;

  // Double-buffered K/V fragment registers.
  bf16x8 bkA[2][3], bvA[6], bkB[2][3], bvB[6];

  auto loadKV = [&](int kt, bf16x8 (&bk)[2][3], bf16x8 (&bv)[6]) {
    const bf16* Kp = Kp0 + (size_t)(kt * 32) * 768;
#pragma unroll
    for (int j = 0; j < 2; j++)
#pragma unroll
      for (int c = 0; c < 3; c++)
        bk[j][c] = *(const bf16x8*)(Kp + (size_t)(j * 16) * 768 + c * 32);
#pragma unroll
    for (int j2 = 0; j2 < 6; j2++)
      bv[j2] = *(const bf16x8*)(Vp0 + (size_t)(j2 * 16) * 2048 + kt * 32);
  };

  auto body = [&](int kt, bf16x8 (&bk)[2][3], bf16x8 (&bv)[6],
                  bf16x8 (&nk)[2][3], bf16x8 (&nv)[6]) {
    // Prefetch NEXT iteration's fragments (stay in flight across the whole
    // body; barriers don't drain vmcnt).
    const int kn = (kt + 1 < 64) ? kt + 1 : 63;
    loadKV(kn, nk, nv);

    // E = Q K^T : [16q x 32k] for this head.
    fx4 e[2];
    e[0] = e[1] = (fx4){0.f, 0.f, 0.f, 0.f};
#pragma unroll
    for (int c = 0; c < 3; c++)
#pragma unroll
      for (int j = 0; j < 2; j++)
        e[j] = MFMA16(aq[c], bk[j][c], e[j]);

    // Scatter E -> Ebuf[q*260 + h*32 + k]
#pragma unroll
    for (int j = 0; j < 2; j++)
#pragma unroll
      for (int r = 0; r < 4; r++)
        Ebuf[(q4 * 4 + r) * 260 + h * 32 + j * 16 + l15] = e[j][r];
    barrier_nodrain();

    // Softmax over heads. 512 (q,k) pairs, 1 per thread.
    {
      const int q = tid >> 5, k = tid & 31;
      float v[8];
#pragma unroll
      for (int hh = 0; hh < 8; hh++) v[hh] = Ebuf[q * 260 + hh * 32 + k];
      float m = v[0];
#pragma unroll
      for (int hh = 1; hh < 8; hh++) m = fmaxf(m, v[hh]);
      float sm = 0.f;
#pragma unroll
      for (int hh = 0; hh < 8; hh++) { v[hh] = __expf(v[hh] - m); sm += v[hh]; }
      const float inv = 1.0f / (sm * 27.712812921102035f);  // / sqrt(768)
#pragma unroll
      for (int hh = 0; hh < 8; hh++)
        Pbuf[hh * 512 + q * 32 + k] = (bf16)(v[hh] * inv);
    }
    barrier_nodrain();

    // O += P @ V (V regs from the previous iteration's prefetch).
    bf16x8 ap = *(const bf16x8*)&Pbuf[h * 512 + l15 * 32 + q4 * 8];
#pragma unroll
    for (int j2 = 0; j2 < 6; j2++)
      o[j2] = MFMA16(ap, bv[j2], o[j2]);
  };

  loadKV(0, bkA, bvA);
  for (int kt = 0; kt < 64; kt += 2) {
    body(kt,     bkA, bvA, bkB, bvB);
    body(kt + 1, bkB, bvB, bkA, bvA);
  }

  // Write AO[qrow0 + q][h*96 + d]
#pragma unroll
  for (int j2 = 0; j2 < 6; j2++)
#pragma unroll
    for (int r = 0; r < 4; r++)
      AO[(size_t)(qrow0 + q4 * 4 + r) * 768 + h * 96 + j2 * 16 + l15] =
          (bf16)(o[j2][r]);
}

// ---------------------------------------------------------------------------
// Memory plan (proven): d_out = xb + Kw (both dead before gemm_o overwrites
// d_out fp32). ws = Q + Vt (25.2 MB). AO aliases Q.
// ---------------------------------------------------------------------------
extern "C" void kernel_launch(void* const* d_in, const int* in_sizes, int n_in,
                              void* d_out, int out_size, void* d_ws,
                              size_t ws_size, hipStream_t stream) {
  const float* x  = (const float*)d_in[0];
  const float* Wq = (const float*)d_in[1];
  const float* bq = (const float*)d_in[2];
  const float* Wk = (const float*)d_in[3];
  const float* bk = (const float*)d_in[4];
  const float* Wv = (const float*)d_in[5];
  const float* bv = (const float*)d_in[6];
  const float* Wo = (const float*)d_in[7];
  const float* bo = (const float*)d_in[8];

  const size_t MN = (size_t)8192 * 768;
  bf16* xb = (bf16*)d_out;
  bf16* Kw = xb + MN;
  bf16* Q  = (bf16*)d_ws;
  bf16* Vt = Q + MN;
  bf16* AO = Q;  // aliases Q

  cvt_x_kernel<<<6144, 256, 0, stream>>>(x, xb);
  dim3 qkvgrid(18, 64);
  gemm_qkv<<<qkvgrid, 256, 0, stream>>>(xb, Wq, Wk, Wv, bq, bk, bv, Q, Kw, Vt);
  attn_kernel<<<512, 512, 0, stream>>>(Q, Kw, Vt, AO);
  dim3 ogrid(6, 64);
  gemm_o<<<ogrid, 256, 0, stream>>>(AO, Wo, bo, (float*)d_out);
}

// Round 2
// 543.212 us; speedup vs baseline: 1.3164x; 1.3164x over previous
//
#include <hip/hip_runtime.h>

typedef __bf16 bf16;
typedef __bf16 bf16x4 __attribute__((ext_vector_type(4)));
typedef __bf16 bf16x8 __attribute__((ext_vector_type(8)));
typedef float  fx4    __attribute__((ext_vector_type(4)));

#define MFMA16(a, b, c) __builtin_amdgcn_mfma_f32_16x16x32_bf16((a), (b), (c), 0, 0, 0)

// B=4, N=2048, E=768, H=8, D=96; M = B*N = 8192. User tensors fp32, out fp32.

// ---------------------------------------------------------------------------
// Barrier WITHOUT the vmem drain. __syncthreads() emits
// "s_waitcnt vmcnt(0) lgkmcnt(0); s_barrier" — the vmcnt(0) kills register
// prefetch. LDS cross-wave visibility only needs lgkmcnt(0).
// 0xC07F = vmcnt 63 (no wait), expcnt 7 (no wait), lgkmcnt 0.
// ---------------------------------------------------------------------------
__device__ __forceinline__ void barrier_nodrain() {
  __asm__ __volatile__("" ::: "memory");
  __builtin_amdgcn_s_waitcnt(0xC07F);
  __builtin_amdgcn_s_barrier();
  __asm__ __volatile__("" ::: "memory");
}

// ---------------------------------------------------------------------------
// x (fp32) -> bf16, 4 elems/thread.
// ---------------------------------------------------------------------------
__global__ __launch_bounds__(256)
void cvt_x_kernel(const float* __restrict__ x, bf16* __restrict__ xb) {
  const int i = (blockIdx.x * 256 + threadIdx.x) * 4;
  float4 v = *(const float4*)&x[i];
  bf16x4 o;
  o[0] = (bf16)v.x; o[1] = (bf16)v.y; o[2] = (bf16)v.z; o[3] = (bf16)v.w;
  *(bf16x4*)&xb[i] = o;
}

// ---------------------------------------------------------------------------
// Fused QKV GEMM (round-7 proven, untouched). blockIdx.x: 0-5 Q, 6-11 K,
// 12-17 V (transposed out). 1152 blocks. Tile 128x128, BK=32, 4 waves.
// ---------------------------------------------------------------------------
__global__ __launch_bounds__(256)
void gemm_qkv(const bf16* __restrict__ A,
              const float* __restrict__ Wq, const float* __restrict__ Wk,
              const float* __restrict__ Wv,
              const float* __restrict__ bq, const float* __restrict__ bk,
              const float* __restrict__ bv,
              bf16* __restrict__ Qo, bf16* __restrict__ Ko,
              bf16* __restrict__ Vto) {
  constexpr int K = 768;
  __shared__ __align__(16) bf16 As[128 * 32];
  __shared__ __align__(16) bf16 Bs[128 * 32];

  const int tid  = threadIdx.x;
  const int wave = tid >> 6;
  const int lane = tid & 63;
  const int l15  = lane & 15;
  const int q4   = lane >> 4;
  const int wr   = wave >> 1;
  const int wc   = wave & 1;
  const int sel  = blockIdx.x / 6;
  const int cb0  = (blockIdx.x % 6) * 128;
  const int rb0  = blockIdx.y * 128;

  const float* W   = (sel == 0) ? Wq : (sel == 1) ? Wk : Wv;
  const float* bia = (sel == 0) ? bq : (sel == 1) ? bk : bv;

  fx4 acc[4][4];
#pragma unroll
  for (int i = 0; i < 4; i++)
#pragma unroll
    for (int j = 0; j < 4; j++) acc[i][j] = (fx4){0.f, 0.f, 0.f, 0.f};

  for (int k0 = 0; k0 < K; k0 += 32) {
    for (int c = tid; c < 512; c += 256) {
      const int row = c >> 2;
      const int kc  = (c & 3) << 3;
      *(uint4*)&As[row * 32 + kc] =
          *(const uint4*)&A[(size_t)(rb0 + row) * K + k0 + kc];
      const float* sb = W + (size_t)(cb0 + row) * K + k0 + kc;
      bf16x8 pb;
#pragma unroll
      for (int t = 0; t < 8; t++) pb[t] = (bf16)sb[t];
      *(bf16x8*)&Bs[row * 32 + kc] = pb;
    }
    __syncthreads();

    bf16x8 a[4], b[4];
#pragma unroll
    for (int i = 0; i < 4; i++)
      a[i] = *(const bf16x8*)&As[(wr * 64 + i * 16 + l15) * 32 + q4 * 8];
#pragma unroll
    for (int j = 0; j < 4; j++)
      b[j] = *(const bf16x8*)&Bs[(wc * 64 + j * 16 + l15) * 32 + q4 * 8];
#pragma unroll
    for (int i = 0; i < 4; i++)
#pragma unroll
      for (int j = 0; j < 4; j++)
        acc[i][j] = MFMA16(a[i], b[j], acc[i][j]);
    __syncthreads();
  }

  const int cb = cb0 + wc * 64;
  const int rb = rb0 + wr * 64;
  bf16* Co = (sel == 0) ? Qo : Ko;
#pragma unroll
  for (int j = 0; j < 4; j++) {
    const int o  = cb + j * 16 + l15;
    const float bj = bia[o];
#pragma unroll
    for (int i = 0; i < 4; i++) {
      const int r0 = rb + i * 16 + q4 * 4;
      if (sel == 2) {
        const int bb = r0 >> 11;
        const int n0 = r0 & 2047;
        bf16x4 pk;
#pragma unroll
        for (int r = 0; r < 4; r++) pk[r] = (bf16)(acc[i][j][r] + bj);
        *(bf16x4*)&Vto[((size_t)(bb * 768 + o)) * 2048 + n0] = pk;
      } else {
#pragma unroll
        for (int r = 0; r < 4; r++)
          Co[(size_t)(r0 + r) * 768 + o] = (bf16)(acc[i][j][r] + bj);
      }
    }
  }
}

// ---------------------------------------------------------------------------
// Output projection: out[M,768] fp32 = AO bf16 @ Wo^T + bo (untouched).
// ---------------------------------------------------------------------------
__global__ __launch_bounds__(256)
void gemm_o(const bf16* __restrict__ A, const float* __restrict__ W,
            const float* __restrict__ bias, float* __restrict__ C) {
  constexpr int K = 768;
  __shared__ __align__(16) bf16 As[128 * 32];
  __shared__ __align__(16) bf16 Bs[128 * 32];

  const int tid  = threadIdx.x;
  const int wave = tid >> 6;
  const int lane = tid & 63;
  const int l15  = lane & 15;
  const int q4   = lane >> 4;
  const int wr   = wave >> 1;
  const int wc   = wave & 1;
  const int rb0  = blockIdx.y * 128;
  const int cb0  = blockIdx.x * 128;

  fx4 acc[4][4];
#pragma unroll
  for (int i = 0; i < 4; i++)
#pragma unroll
    for (int j = 0; j < 4; j++) acc[i][j] = (fx4){0.f, 0.f, 0.f, 0.f};

  for (int k0 = 0; k0 < K; k0 += 32) {
    for (int c = tid; c < 512; c += 256) {
      const int row = c >> 2;
      const int kc  = (c & 3) << 3;
      *(uint4*)&As[row * 32 + kc] =
          *(const uint4*)&A[(size_t)(rb0 + row) * K + k0 + kc];
      const float* sb = W + (size_t)(cb0 + row) * K + k0 + kc;
      bf16x8 pb;
#pragma unroll
      for (int t = 0; t < 8; t++) pb[t] = (bf16)sb[t];
      *(bf16x8*)&Bs[row * 32 + kc] = pb;
    }
    __syncthreads();

    bf16x8 a[4], b[4];
#pragma unroll
    for (int i = 0; i < 4; i++)
      a[i] = *(const bf16x8*)&As[(wr * 64 + i * 16 + l15) * 32 + q4 * 8];
#pragma unroll
    for (int j = 0; j < 4; j++)
      b[j] = *(const bf16x8*)&Bs[(wc * 64 + j * 16 + l15) * 32 + q4 * 8];
#pragma unroll
    for (int i = 0; i < 4; i++)
#pragma unroll
      for (int j = 0; j < 4; j++)
        acc[i][j] = MFMA16(a[i], b[j], acc[i][j]);
    __syncthreads();
  }

  const int cb = cb0 + wc * 64;
  const int rb = rb0 + wr * 64;
#pragma unroll
  for (int j = 0; j < 4; j++) {
    const int o  = cb + j * 16 + l15;
    const float bj = bias[o];
#pragma unroll
    for (int i = 0; i < 4; i++) {
      const int r0 = rb + i * 16 + q4 * 4;
#pragma unroll
      for (int r = 0; r < 4; r++)
        C[(size_t)(r0 + r) * 768 + o] = acc[i][j][r] + bj;
    }
  }
}

// ---------------------------------------------------------------------------
// Attention, softmax over HEADS (dim=1), / sqrt(768).
// R12: 16 waves (1024 threads) per block, wave = (head, q-half).
//  - R11 post-mortem: __launch_bounds__(512,4) capped VGPR at 64 (2nd arg
//    behaved like blocks/CU, not waves/EU) -> double-buffer spilled to
//    scratch (WRITE_SIZE 12->302 MB). Never constrain below measured need.
//  - R10 bottleneck stands: grid 256 = 1 block/CU, 2 waves/SIMD, lockstep
//    barriers -> MfmaUtil 10%. Fix by doubling waves IN the block: each
//    wave now owns 16 q-rows of its head (waves h*2+qh). Per-wave state
//    shrinks (aq 24->12, o 48->24 regs), K/V single-buffered and reloaded
//    right after QK^T (scatter+softmax+PV ~1000 cyc covers the latency;
//    loads stay in flight across nodrain barriers). Est. ~116 VGPR < 128
//    cap implied by __launch_bounds__(1024) (no 2nd arg!).
//  - Pbuf k-stride padded 32 -> 40 (80 B rows, 16B-aligned): R10's PV
//    A-frag ds_read_b128 had 64 B row stride = 8-way bank conflict
//    (SQ_LDS_BANK_CONFLICT pegged at 2^20). 40 gives 2-way = free.
// LDS: Ebuf 32x260 f32 (33.3 KB) + Pbuf 8x32x40 bf16 (20 KB) = 52.5 KB.
// AO aliases Q: all Q reads happen before the k-loop, AO writes after;
// blocks own disjoint 32-row q-ranges.
// ---------------------------------------------------------------------------
__global__ __launch_bounds__(1024)
void attn_kernel(const bf16* Q, const bf16* __restrict__ Kb,
                 const bf16* __restrict__ Vt, bf16* AO) {
  __shared__ __align__(16) float Ebuf[32 * 260];     // [q][h*32+k], 33.3 KB
  __shared__ __align__(16) bf16  Pbuf[8 * 32 * 40];  // [h][q][k pad 40], 20 KB

  const int tid  = threadIdx.x;
  const int wave = tid >> 6;      // 0..15
  const int h    = wave >> 1;     // head 0..7
  const int qh   = wave & 1;      // q-half 0..1
  const int lane = tid & 63;
  const int l15  = lane & 15;
  const int q4   = lane >> 4;
  const int b    = blockIdx.x >> 6;
  const int qt   = blockIdx.x & 63;
  const int qrow0 = b * 2048 + qt * 32;
  const int qw    = qh * 16;      // this wave's q offset within the 32-row tile

  // Persistent Q fragments: 1 q-16tile x 3 d-chunks (12 VGPRs).
  bf16x8 aq[3];
#pragma unroll
  for (int c = 0; c < 3; c++)
    aq[c] = *(const bf16x8*)
        &Q[(size_t)(qrow0 + qw + l15) * 768 + h * 96 + c * 32 + q4 * 8];

  fx4 o[6];
#pragma unroll
  for (int j = 0; j < 6; j++) o[j] = (fx4){0.f, 0.f, 0.f, 0.f};

  // Per-lane fixed base pointers.
  const bf16* Kp0 = Kb + (size_t)(b * 2048 + l15) * 768 + h * 96 + q4 * 8;
  const bf16* Vp0 = Vt + (size_t)((b * 8 + h) * 96 + l15) * 2048 + q4 * 8;

  // Single-buffered K/V fragments, reloaded after each use.
  bf16x8 bk[2][3], bv[6];

  auto loadK = [&](int kt) {
    const bf16* Kp = Kp0 + (size_t)(kt * 32) * 768;
#pragma unroll
    for (int j = 0; j < 2; j++)
#pragma unroll
      for (int c = 0; c < 3; c++)
        bk[j][c] = *(const bf16x8*)(Kp + (size_t)(j * 16) * 768 + c * 32);
  };
  auto loadV = [&](int kt) {
#pragma unroll
    for (int j2 = 0; j2 < 6; j2++)
      bv[j2] = *(const bf16x8*)(Vp0 + (size_t)(j2 * 16) * 2048 + kt * 32);
  };

  loadK(0);  // prologue

  for (int kt = 0; kt < 64; kt++) {
    // E = Q K^T : [16q x 32k] for this head (K loaded last iteration).
    fx4 e[2];
    e[0] = e[1] = (fx4){0.f, 0.f, 0.f, 0.f};
#pragma unroll
    for (int c = 0; c < 3; c++)
#pragma unroll
      for (int j = 0; j < 2; j++)
        e[j] = MFMA16(aq[c], bk[j][c], e[j]);

    // Issue next K and current V now; latency covered by scatter + softmax
    // (+PV for K). Loads stay in flight across the nodrain barriers.
    loadK(kt + 1 < 64 ? kt + 1 : 63);
    loadV(kt);

    // Scatter E -> Ebuf[q*260 + h*32 + k]
#pragma unroll
    for (int j = 0; j < 2; j++)
#pragma unroll
      for (int r = 0; r < 4; r++)
        Ebuf[(qw + q4 * 4 + r) * 260 + h * 32 + j * 16 + l15] = e[j][r];
    barrier_nodrain();

    // Softmax over heads. 1024 (q,k) pairs, 1 per thread.
    {
      const int q = tid >> 5, k = tid & 31;
      float v[8];
#pragma unroll
      for (int hh = 0; hh < 8; hh++) v[hh] = Ebuf[q * 260 + hh * 32 + k];
      float m = v[0];
#pragma unroll
      for (int hh = 1; hh < 8; hh++) m = fmaxf(m, v[hh]);
      float sm = 0.f;
#pragma unroll
      for (int hh = 0; hh < 8; hh++) { v[hh] = __expf(v[hh] - m); sm += v[hh]; }
      const float inv = 1.0f / (sm * 27.712812921102035f);  // / sqrt(768)
#pragma unroll
      for (int hh = 0; hh < 8; hh++)
        Pbuf[hh * 1280 + q * 40 + k] = (bf16)(v[hh] * inv);
    }
    barrier_nodrain();

    // O += P @ V.
    bf16x8 ap = *(const bf16x8*)&Pbuf[h * 1280 + (qw + l15) * 40 + q4 * 8];
#pragma unroll
    for (int j2 = 0; j2 < 6; j2++)
      o[j2] = MFMA16(ap, bv[j2], o[j2]);
  }

  // Write AO[qrow0 + qw + q][h*96 + d]
#pragma unroll
  for (int j2 = 0; j2 < 6; j2++)
#pragma unroll
    for (int r = 0; r < 4; r++)
      AO[(size_t)(qrow0 + qw + q4 * 4 + r) * 768 + h * 96 + j2 * 16 + l15] =
          (bf16)(o[j2][r]);
}

// ---------------------------------------------------------------------------
// Memory plan (proven): d_out = xb + Kw (both dead before gemm_o overwrites
// d_out fp32). ws = Q + Vt (25.2 MB). AO aliases Q.
// ---------------------------------------------------------------------------
extern "C" void kernel_launch(void* const* d_in, const int* in_sizes, int n_in,
                              void* d_out, int out_size, void* d_ws,
                              size_t ws_size, hipStream_t stream) {
  const float* x  = (const float*)d_in[0];
  const float* Wq = (const float*)d_in[1];
  const float* bq = (const float*)d_in[2];
  const float* Wk = (const float*)d_in[3];
  const float* bk = (const float*)d_in[4];
  const float* Wv = (const float*)d_in[5];
  const float* bv = (const float*)d_in[6];
  const float* Wo = (const float*)d_in[7];
  const float* bo = (const float*)d_in[8];

  const size_t MN = (size_t)8192 * 768;
  bf16* xb = (bf16*)d_out;
  bf16* Kw = xb + MN;
  bf16* Q  = (bf16*)d_ws;
  bf16* Vt = Q + MN;
  bf16* AO = Q;  // aliases Q

  cvt_x_kernel<<<6144, 256, 0, stream>>>(x, xb);
  dim3 qkvgrid(18, 64);
  gemm_qkv<<<qkvgrid, 256, 0, stream>>>(xb, Wq, Wk, Wv, bq, bk, bv, Q, Kw, Vt);
  attn_kernel<<<256, 1024, 0, stream>>>(Q, Kw, Vt, AO);
  dim3 ogrid(6, 64);
  gemm_o<<<ogrid, 256, 0, stream>>>(AO, Wo, bo, (float*)d_out);
}

// Round 3
// 534.369 us; speedup vs baseline: 1.3382x; 1.0165x over previous
//
#include <hip/hip_runtime.h>

typedef __bf16 bf16;
typedef __bf16 bf16x4 __attribute__((ext_vector_type(4)));
typedef __bf16 bf16x8 __attribute__((ext_vector_type(8)));
typedef float  fx4    __attribute__((ext_vector_type(4)));

#define MFMA16(a, b, c) __builtin_amdgcn_mfma_f32_16x16x32_bf16((a), (b), (c), 0, 0, 0)

// B=4, N=2048, E=768, H=8, D=96; M = B*N = 8192. User tensors fp32, out fp32.

// ---------------------------------------------------------------------------
// Barrier WITHOUT the vmem drain. __syncthreads() emits
// "s_waitcnt vmcnt(0) lgkmcnt(0); s_barrier" — the vmcnt(0) kills register
// prefetch. LDS cross-wave visibility only needs lgkmcnt(0).
// 0xC07F = vmcnt 63 (no wait), expcnt 7 (no wait), lgkmcnt 0.
// ---------------------------------------------------------------------------
__device__ __forceinline__ void barrier_nodrain() {
  __asm__ __volatile__("" ::: "memory");
  __builtin_amdgcn_s_waitcnt(0xC07F);
  __builtin_amdgcn_s_barrier();
  __asm__ __volatile__("" ::: "memory");
}

// ---------------------------------------------------------------------------
// x (fp32) -> bf16, 4 elems/thread.
// ---------------------------------------------------------------------------
__global__ __launch_bounds__(256)
void cvt_x_kernel(const float* __restrict__ x, bf16* __restrict__ xb) {
  const int i = (blockIdx.x * 256 + threadIdx.x) * 4;
  float4 v = *(const float4*)&x[i];
  bf16x4 o;
  o[0] = (bf16)v.x; o[1] = (bf16)v.y; o[2] = (bf16)v.z; o[3] = (bf16)v.w;
  *(bf16x4*)&xb[i] = o;
}

// ---------------------------------------------------------------------------
// Fused QKV GEMM (round-7 proven, untouched). blockIdx.x: 0-5 Q, 6-11 K,
// 12-17 V (transposed out). 1152 blocks. Tile 128x128, BK=32, 4 waves.
// ---------------------------------------------------------------------------
__global__ __launch_bounds__(256)
void gemm_qkv(const bf16* __restrict__ A,
              const float* __restrict__ Wq, const float* __restrict__ Wk,
              const float* __restrict__ Wv,
              const float* __restrict__ bq, const float* __restrict__ bk,
              const float* __restrict__ bv,
              bf16* __restrict__ Qo, bf16* __restrict__ Ko,
              bf16* __restrict__ Vto) {
  constexpr int K = 768;
  __shared__ __align__(16) bf16 As[128 * 32];
  __shared__ __align__(16) bf16 Bs[128 * 32];

  const int tid  = threadIdx.x;
  const int wave = tid >> 6;
  const int lane = tid & 63;
  const int l15  = lane & 15;
  const int q4   = lane >> 4;
  const int wr   = wave >> 1;
  const int wc   = wave & 1;
  const int sel  = blockIdx.x / 6;
  const int cb0  = (blockIdx.x % 6) * 128;
  const int rb0  = blockIdx.y * 128;

  const float* W   = (sel == 0) ? Wq : (sel == 1) ? Wk : Wv;
  const float* bia = (sel == 0) ? bq : (sel == 1) ? bk : bv;

  fx4 acc[4][4];
#pragma unroll
  for (int i = 0; i < 4; i++)
#pragma unroll
    for (int j = 0; j < 4; j++) acc[i][j] = (fx4){0.f, 0.f, 0.f, 0.f};

  for (int k0 = 0; k0 < K; k0 += 32) {
    for (int c = tid; c < 512; c += 256) {
      const int row = c >> 2;
      const int kc  = (c & 3) << 3;
      *(uint4*)&As[row * 32 + kc] =
          *(const uint4*)&A[(size_t)(rb0 + row) * K + k0 + kc];
      const float* sb = W + (size_t)(cb0 + row) * K + k0 + kc;
      bf16x8 pb;
#pragma unroll
      for (int t = 0; t < 8; t++) pb[t] = (bf16)sb[t];
      *(bf16x8*)&Bs[row * 32 + kc] = pb;
    }
    __syncthreads();

    bf16x8 a[4], b[4];
#pragma unroll
    for (int i = 0; i < 4; i++)
      a[i] = *(const bf16x8*)&As[(wr * 64 + i * 16 + l15) * 32 + q4 * 8];
#pragma unroll
    for (int j = 0; j < 4; j++)
      b[j] = *(const bf16x8*)&Bs[(wc * 64 + j * 16 + l15) * 32 + q4 * 8];
#pragma unroll
    for (int i = 0; i < 4; i++)
#pragma unroll
      for (int j = 0; j < 4; j++)
        acc[i][j] = MFMA16(a[i], b[j], acc[i][j]);
    __syncthreads();
  }

  const int cb = cb0 + wc * 64;
  const int rb = rb0 + wr * 64;
  bf16* Co = (sel == 0) ? Qo : Ko;
#pragma unroll
  for (int j = 0; j < 4; j++) {
    const int o  = cb + j * 16 + l15;
    const float bj = bia[o];
#pragma unroll
    for (int i = 0; i < 4; i++) {
      const int r0 = rb + i * 16 + q4 * 4;
      if (sel == 2) {
        const int bb = r0 >> 11;
        const int n0 = r0 & 2047;
        bf16x4 pk;
#pragma unroll
        for (int r = 0; r < 4; r++) pk[r] = (bf16)(acc[i][j][r] + bj);
        *(bf16x4*)&Vto[((size_t)(bb * 768 + o)) * 2048 + n0] = pk;
      } else {
#pragma unroll
        for (int r = 0; r < 4; r++)
          Co[(size_t)(r0 + r) * 768 + o] = (bf16)(acc[i][j][r] + bj);
      }
    }
  }
}

// ---------------------------------------------------------------------------
// Output projection: out[M,768] fp32 = AO bf16 @ Wo^T + bo (untouched).
// ---------------------------------------------------------------------------
__global__ __launch_bounds__(256)
void gemm_o(const bf16* __restrict__ A, const float* __restrict__ W,
            const float* __restrict__ bias, float* __restrict__ C) {
  constexpr int K = 768;
  __shared__ __align__(16) bf16 As[128 * 32];
  __shared__ __align__(16) bf16 Bs[128 * 32];

  const int tid  = threadIdx.x;
  const int wave = tid >> 6;
  const int lane = tid & 63;
  const int l15  = lane & 15;
  const int q4   = lane >> 4;
  const int wr   = wave >> 1;
  const int wc   = wave & 1;
  const int rb0  = blockIdx.y * 128;
  const int cb0  = blockIdx.x * 128;

  fx4 acc[4][4];
#pragma unroll
  for (int i = 0; i < 4; i++)
#pragma unroll
    for (int j = 0; j < 4; j++) acc[i][j] = (fx4){0.f, 0.f, 0.f, 0.f};

  for (int k0 = 0; k0 < K; k0 += 32) {
    for (int c = tid; c < 512; c += 256) {
      const int row = c >> 2;
      const int kc  = (c & 3) << 3;
      *(uint4*)&As[row * 32 + kc] =
          *(const uint4*)&A[(size_t)(rb0 + row) * K + k0 + kc];
      const float* sb = W + (size_t)(cb0 + row) * K + k0 + kc;
      bf16x8 pb;
#pragma unroll
      for (int t = 0; t < 8; t++) pb[t] = (bf16)sb[t];
      *(bf16x8*)&Bs[row * 32 + kc] = pb;
    }
    __syncthreads();

    bf16x8 a[4], b[4];
#pragma unroll
    for (int i = 0; i < 4; i++)
      a[i] = *(const bf16x8*)&As[(wr * 64 + i * 16 + l15) * 32 + q4 * 8];
#pragma unroll
    for (int j = 0; j < 4; j++)
      b[j] = *(const bf16x8*)&Bs[(wc * 64 + j * 16 + l15) * 32 + q4 * 8];
#pragma unroll
    for (int i = 0; i < 4; i++)
#pragma unroll
      for (int j = 0; j < 4; j++)
        acc[i][j] = MFMA16(a[i], b[j], acc[i][j]);
    __syncthreads();
  }

  const int cb = cb0 + wc * 64;
  const int rb = rb0 + wr * 64;
#pragma unroll
  for (int j = 0; j < 4; j++) {
    const int o  = cb + j * 16 + l15;
    const float bj = bias[o];
#pragma unroll
    for (int i = 0; i < 4; i++) {
      const int r0 = rb + i * 16 + q4 * 4;
#pragma unroll
      for (int r = 0; r < 4; r++)
        C[(size_t)(r0 + r) * 768 + o] = acc[i][j][r] + bj;
    }
  }
}

// ---------------------------------------------------------------------------
// Attention, softmax over HEADS (dim=1), / sqrt(768).
// R13 = R11 geometry with the launch_bounds bug fixed.
//  - R11 post-mortem: __launch_bounds__(512,4) clamped VGPR to 64 -> the
//    96-VGPR K/V double-buffer spilled (WRITE_SIZE 12->302 MB). The grid
//    structure (512 blocks = 2 independent blocks/CU) was right.
//  - R12 post-mortem: 16 waves in ONE barrier group regressed further
//    (MfmaUtil 5.8%): more waves in the SAME dependency chain add sync
//    cost, not overlap. Independent blocks are what fill the stalls.
//  - Fix: __launch_bounds__(512) with no min-waves arg -> VGPR cap 256,
//    need ~130 (aq 12 + dbuf K/V 96 + e 8 + addr; o in AGPRs). No spill.
//  - Grid 512, 16 q-rows/block: 2 blocks/CU (LDS 27 KB x2 = 54 KB, fine).
//    Block B's QK^T/PV MFMAs issue while block A is in softmax/barrier.
//  - Pbuf k-stride 40 (R12): PV-side LDS accesses <=2-way banked.
//    Ebuf stride stays 260 (rechecked: 260 -> 2-way scatter; 264 -> 4-way).
// AO aliases Q: block reads only its own 16 Q rows before the loop, writes
// only those rows after it — disjoint across blocks.
// ---------------------------------------------------------------------------
__global__ __launch_bounds__(512)
void attn_kernel(const bf16* Q, const bf16* __restrict__ Kb,
                 const bf16* __restrict__ Vt, bf16* AO) {
  __shared__ __align__(16) float Ebuf[16 * 260];     // [q][h*32+k], 16.6 KB
  __shared__ __align__(16) bf16  Pbuf[8 * 16 * 40];  // [h][q][k pad 40], 10 KB

  const int tid  = threadIdx.x;
  const int h    = tid >> 6;
  const int lane = tid & 63;
  const int l15  = lane & 15;
  const int q4   = lane >> 4;
  const int b    = blockIdx.x >> 7;
  const int qt   = blockIdx.x & 127;
  const int qrow0 = b * 2048 + qt * 16;

  // Persistent Q fragments: 1 q-16tile x 3 d-chunks.
  bf16x8 aq[3];
#pragma unroll
  for (int c = 0; c < 3; c++)
    aq[c] = *(const bf16x8*)
        &Q[(size_t)(qrow0 + l15) * 768 + h * 96 + c * 32 + q4 * 8];

  fx4 o[6];
#pragma unroll
  for (int j = 0; j < 6; j++) o[j] = (fx4){0.f, 0.f, 0.f, 0.f};

  // Per-lane fixed base pointers.
  const bf16* Kp0 = Kb + (size_t)(b * 2048 + l15) * 768 + h * 96 + q4 * 8;
  const bf16* Vp0 = Vt + (size_t)((b * 8 + h) * 96 + l15) * 2048 + q4 * 8;

  // Double-buffered K/V fragment registers.
  bf16x8 bkA[2][3], bvA[6], bkB[2][3], bvB[6];

  auto loadKV = [&](int kt, bf16x8 (&bk)[2][3], bf16x8 (&bv)[6]) {
    const bf16* Kp = Kp0 + (size_t)(kt * 32) * 768;
#pragma unroll
    for (int j = 0; j < 2; j++)
#pragma unroll
      for (int c = 0; c < 3; c++)
        bk[j][c] = *(const bf16x8*)(Kp + (size_t)(j * 16) * 768 + c * 32);
#pragma unroll
    for (int j2 = 0; j2 < 6; j2++)
      bv[j2] = *(const bf16x8*)(Vp0 + (size_t)(j2 * 16) * 2048 + kt * 32);
  };

  auto body = [&](int kt, bf16x8 (&bk)[2][3], bf16x8 (&bv)[6],
                  bf16x8 (&nk)[2][3], bf16x8 (&nv)[6]) {
    // Prefetch NEXT iteration's fragments (stay in flight across the whole
    // body; barriers don't drain vmcnt).
    const int kn = (kt + 1 < 64) ? kt + 1 : 63;
    loadKV(kn, nk, nv);

    // E = Q K^T : [16q x 32k] for this head.
    fx4 e[2];
    e[0] = e[1] = (fx4){0.f, 0.f, 0.f, 0.f};
#pragma unroll
    for (int c = 0; c < 3; c++)
#pragma unroll
      for (int j = 0; j < 2; j++)
        e[j] = MFMA16(aq[c], bk[j][c], e[j]);

    // Scatter E -> Ebuf[q*260 + h*32 + k]
#pragma unroll
    for (int j = 0; j < 2; j++)
#pragma unroll
      for (int r = 0; r < 4; r++)
        Ebuf[(q4 * 4 + r) * 260 + h * 32 + j * 16 + l15] = e[j][r];
    barrier_nodrain();

    // Softmax over heads. 512 (q,k) pairs, 1 per thread.
    {
      const int q = tid >> 5, k = tid & 31;
      float v[8];
#pragma unroll
      for (int hh = 0; hh < 8; hh++) v[hh] = Ebuf[q * 260 + hh * 32 + k];
      float m = v[0];
#pragma unroll
      for (int hh = 1; hh < 8; hh++) m = fmaxf(m, v[hh]);
      float sm = 0.f;
#pragma unroll
      for (int hh = 0; hh < 8; hh++) { v[hh] = __expf(v[hh] - m); sm += v[hh]; }
      const float inv = 1.0f / (sm * 27.712812921102035f);  // / sqrt(768)
#pragma unroll
      for (int hh = 0; hh < 8; hh++)
        Pbuf[hh * 640 + q * 40 + k] = (bf16)(v[hh] * inv);
    }
    barrier_nodrain();

    // O += P @ V (V regs from the previous iteration's prefetch).
    bf16x8 ap = *(const bf16x8*)&Pbuf[h * 640 + l15 * 40 + q4 * 8];
#pragma unroll
    for (int j2 = 0; j2 < 6; j2++)
      o[j2] = MFMA16(ap, bv[j2], o[j2]);
  };

  loadKV(0, bkA, bvA);
  for (int kt = 0; kt < 64; kt += 2) {
    body(kt,     bkA, bvA, bkB, bvB);
    body(kt + 1, bkB, bvB, bkA, bvA);
  }

  // Write AO[qrow0 + q][h*96 + d]
#pragma unroll
  for (int j2 = 0; j2 < 6; j2++)
#pragma unroll
    for (int r = 0; r < 4; r++)
      AO[(size_t)(qrow0 + q4 * 4 + r) * 768 + h * 96 + j2 * 16 + l15] =
          (bf16)(o[j2][r]);
}

// ---------------------------------------------------------------------------
// Memory plan (proven): d_out = xb + Kw (both dead before gemm_o overwrites
// d_out fp32). ws = Q + Vt (25.2 MB). AO aliases Q.
// ---------------------------------------------------------------------------
extern "C" void kernel_launch(void* const* d_in, const int* in_sizes, int n_in,
                              void* d_out, int out_size, void* d_ws,
                              size_t ws_size, hipStream_t stream) {
  const float* x  = (const float*)d_in[0];
  const float* Wq = (const float*)d_in[1];
  const float* bq = (const float*)d_in[2];
  const float* Wk = (const float*)d_in[3];
  const float* bk = (const float*)d_in[4];
  const float* Wv = (const float*)d_in[5];
  const float* bv = (const float*)d_in[6];
  const float* Wo = (const float*)d_in[7];
  const float* bo = (const float*)d_in[8];

  const size_t MN = (size_t)8192 * 768;
  bf16* xb = (bf16*)d_out;
  bf16* Kw = xb + MN;
  bf16* Q  = (bf16*)d_ws;
  bf16* Vt = Q + MN;
  bf16* AO = Q;  // aliases Q

  cvt_x_kernel<<<6144, 256, 0, stream>>>(x, xb);
  dim3 qkvgrid(18, 64);
  gemm_qkv<<<qkvgrid, 256, 0, stream>>>(xb, Wq, Wk, Wv, bq, bk, bv, Q, Kw, Vt);
  attn_kernel<<<512, 512, 0, stream>>>(Q, Kw, Vt, AO);
  dim3 ogrid(6, 64);
  gemm_o<<<ogrid, 256, 0, stream>>>(AO, Wo, bo, (float*)d_out);
}

// Round 4
// 390.677 us; speedup vs baseline: 1.8304x; 1.3678x over previous
//
#include <hip/hip_runtime.h>

typedef __bf16 bf16;
typedef __bf16 bf16x4 __attribute__((ext_vector_type(4)));
typedef __bf16 bf16x8 __attribute__((ext_vector_type(8)));
typedef float  fx4    __attribute__((ext_vector_type(4)));

#define MFMA16(a, b, c) __builtin_amdgcn_mfma_f32_16x16x32_bf16((a), (b), (c), 0, 0, 0)

// B=4, N=2048, E=768, H=8, D=96; M = B*N = 8192. User tensors fp32, out fp32.

// ---------------------------------------------------------------------------
// Barrier WITHOUT the vmem drain. __syncthreads() emits
// "s_waitcnt vmcnt(0) lgkmcnt(0); s_barrier" — the vmcnt(0) kills register
// prefetch. LDS cross-wave visibility only needs lgkmcnt(0).
// 0xC07F = vmcnt 63 (no wait), expcnt 7 (no wait), lgkmcnt 0.
// ---------------------------------------------------------------------------
__device__ __forceinline__ void barrier_nodrain() {
  __asm__ __volatile__("" ::: "memory");
  __builtin_amdgcn_s_waitcnt(0xC07F);
  __builtin_amdgcn_s_barrier();
  __asm__ __volatile__("" ::: "memory");
}

// ---------------------------------------------------------------------------
// x (fp32) -> bf16, 4 elems/thread.
// ---------------------------------------------------------------------------
__global__ __launch_bounds__(256)
void cvt_x_kernel(const float* __restrict__ x, bf16* __restrict__ xb) {
  const int i = (blockIdx.x * 256 + threadIdx.x) * 4;
  float4 v = *(const float4*)&x[i];
  bf16x4 o;
  o[0] = (bf16)v.x; o[1] = (bf16)v.y; o[2] = (bf16)v.z; o[3] = (bf16)v.w;
  *(bf16x4*)&xb[i] = o;
}

// ---------------------------------------------------------------------------
// Fused QKV GEMM (round-7 proven, untouched). blockIdx.x: 0-5 Q, 6-11 K,
// 12-17 V (transposed out). 1152 blocks. Tile 128x128, BK=32, 4 waves.
// ---------------------------------------------------------------------------
__global__ __launch_bounds__(256)
void gemm_qkv(const bf16* __restrict__ A,
              const float* __restrict__ Wq, const float* __restrict__ Wk,
              const float* __restrict__ Wv,
              const float* __restrict__ bq, const float* __restrict__ bk,
              const float* __restrict__ bv,
              bf16* __restrict__ Qo, bf16* __restrict__ Ko,
              bf16* __restrict__ Vto) {
  constexpr int K = 768;
  __shared__ __align__(16) bf16 As[128 * 32];
  __shared__ __align__(16) bf16 Bs[128 * 32];

  const int tid  = threadIdx.x;
  const int wave = tid >> 6;
  const int lane = tid & 63;
  const int l15  = lane & 15;
  const int q4   = lane >> 4;
  const int wr   = wave >> 1;
  const int wc   = wave & 1;
  const int sel  = blockIdx.x / 6;
  const int cb0  = (blockIdx.x % 6) * 128;
  const int rb0  = blockIdx.y * 128;

  const float* W   = (sel == 0) ? Wq : (sel == 1) ? Wk : Wv;
  const float* bia = (sel == 0) ? bq : (sel == 1) ? bk : bv;

  fx4 acc[4][4];
#pragma unroll
  for (int i = 0; i < 4; i++)
#pragma unroll
    for (int j = 0; j < 4; j++) acc[i][j] = (fx4){0.f, 0.f, 0.f, 0.f};

  for (int k0 = 0; k0 < K; k0 += 32) {
    for (int c = tid; c < 512; c += 256) {
      const int row = c >> 2;
      const int kc  = (c & 3) << 3;
      *(uint4*)&As[row * 32 + kc] =
          *(const uint4*)&A[(size_t)(rb0 + row) * K + k0 + kc];
      const float* sb = W + (size_t)(cb0 + row) * K + k0 + kc;
      bf16x8 pb;
#pragma unroll
      for (int t = 0; t < 8; t++) pb[t] = (bf16)sb[t];
      *(bf16x8*)&Bs[row * 32 + kc] = pb;
    }
    __syncthreads();

    bf16x8 a[4], b[4];
#pragma unroll
    for (int i = 0; i < 4; i++)
      a[i] = *(const bf16x8*)&As[(wr * 64 + i * 16 + l15) * 32 + q4 * 8];
#pragma unroll
    for (int j = 0; j < 4; j++)
      b[j] = *(const bf16x8*)&Bs[(wc * 64 + j * 16 + l15) * 32 + q4 * 8];
#pragma unroll
    for (int i = 0; i < 4; i++)
#pragma unroll
      for (int j = 0; j < 4; j++)
        acc[i][j] = MFMA16(a[i], b[j], acc[i][j]);
    __syncthreads();
  }

  const int cb = cb0 + wc * 64;
  const int rb = rb0 + wr * 64;
  bf16* Co = (sel == 0) ? Qo : Ko;
#pragma unroll
  for (int j = 0; j < 4; j++) {
    const int o  = cb + j * 16 + l15;
    const float bj = bia[o];
#pragma unroll
    for (int i = 0; i < 4; i++) {
      const int r0 = rb + i * 16 + q4 * 4;
      if (sel == 2) {
        const int bb = r0 >> 11;
        const int n0 = r0 & 2047;
        bf16x4 pk;
#pragma unroll
        for (int r = 0; r < 4; r++) pk[r] = (bf16)(acc[i][j][r] + bj);
        *(bf16x4*)&Vto[((size_t)(bb * 768 + o)) * 2048 + n0] = pk;
      } else {
#pragma unroll
        for (int r = 0; r < 4; r++)
          Co[(size_t)(r0 + r) * 768 + o] = (bf16)(acc[i][j][r] + bj);
      }
    }
  }
}

// ---------------------------------------------------------------------------
// Output projection: out[M,768] fp32 = AO bf16 @ Wo^T + bo (untouched).
// ---------------------------------------------------------------------------
__global__ __launch_bounds__(256)
void gemm_o(const bf16* __restrict__ A, const float* __restrict__ W,
            const float* __restrict__ bias, float* __restrict__ C) {
  constexpr int K = 768;
  __shared__ __align__(16) bf16 As[128 * 32];
  __shared__ __align__(16) bf16 Bs[128 * 32];

  const int tid  = threadIdx.x;
  const int wave = tid >> 6;
  const int lane = tid & 63;
  const int l15  = lane & 15;
  const int q4   = lane >> 4;
  const int wr   = wave >> 1;
  const int wc   = wave & 1;
  const int rb0  = blockIdx.y * 128;
  const int cb0  = blockIdx.x * 128;

  fx4 acc[4][4];
#pragma unroll
  for (int i = 0; i < 4; i++)
#pragma unroll
    for (int j = 0; j < 4; j++) acc[i][j] = (fx4){0.f, 0.f, 0.f, 0.f};

  for (int k0 = 0; k0 < K; k0 += 32) {
    for (int c = tid; c < 512; c += 256) {
      const int row = c >> 2;
      const int kc  = (c & 3) << 3;
      *(uint4*)&As[row * 32 + kc] =
          *(const uint4*)&A[(size_t)(rb0 + row) * K + k0 + kc];
      const float* sb = W + (size_t)(cb0 + row) * K + k0 + kc;
      bf16x8 pb;
#pragma unroll
      for (int t = 0; t < 8; t++) pb[t] = (bf16)sb[t];
      *(bf16x8*)&Bs[row * 32 + kc] = pb;
    }
    __syncthreads();

    bf16x8 a[4], b[4];
#pragma unroll
    for (int i = 0; i < 4; i++)
      a[i] = *(const bf16x8*)&As[(wr * 64 + i * 16 + l15) * 32 + q4 * 8];
#pragma unroll
    for (int j = 0; j < 4; j++)
      b[j] = *(const bf16x8*)&Bs[(wc * 64 + j * 16 + l15) * 32 + q4 * 8];
#pragma unroll
    for (int i = 0; i < 4; i++)
#pragma unroll
      for (int j = 0; j < 4; j++)
        acc[i][j] = MFMA16(a[i], b[j], acc[i][j]);
    __syncthreads();
  }

  const int cb = cb0 + wc * 64;
  const int rb = rb0 + wr * 64;
#pragma unroll
  for (int j = 0; j < 4; j++) {
    const int o  = cb + j * 16 + l15;
    const float bj = bias[o];
#pragma unroll
    for (int i = 0; i < 4; i++) {
      const int r0 = rb + i * 16 + q4 * 4;
#pragma unroll
      for (int r = 0; r < 4; r++)
        C[(size_t)(r0 + r) * 768 + o] = acc[i][j][r] + bj;
    }
  }
}

// ---------------------------------------------------------------------------
// Attention, softmax over HEADS (dim=1), / sqrt(768).
// R14 = R0 geometry (32 q-rows, 256 blocks, 8 waves, dbuf K/V prefetch,
// nodrain barriers) with the register cap REMOVED:
//  - R0 declared __launch_bounds__(512, 2). On this toolchain arg2 acts as
//    a blocks/CU floor (R11: (512,4) -> cap 64 + spill), so (512,2) capped
//    VGPRs at 128. The dbuf needs 96 VGPRs alone (R0 reported 108 total!)
//    -> the compiler SANK the prefetch loads to their use sites. Every
//    body serially ate ~900 cyc of memory latency -> MfmaUtil 10%, body
//    ~6000 cyc vs ~700 cyc of MFMA issue. And grid 256 = 1 block/CU means
//    the 2-block guarantee the cap paid for was never usable.
//  - Fix: __launch_bounds__(512, 1) -> cap 256. Need ~212 (incl. acc).
//    8 waves/CU = 2 waves/SIMD is unchanged for any count <= 256, so
//    occupancy cannot regress. Now the loadKV(kt+1) at body start really
//    stays in flight across scatter/softmax/PV (nodrain barriers finally
//    pay off).
//  - Pbuf k-stride 32 -> 40 (validated R12/R13): PV ds_read_b128 row
//    stride 64 B was 8-way bank-conflicted; 80 B -> 2-way (free).
// Go/no-go: VGPR_Count must jump to ~180-230 with WRITE_SIZE ~12 MB.
// If VGPR stays ~110, compiler still sinks loads -> pivot to GEMMs.
// AO aliases Q: block reads only its own 32 Q rows before the loop, writes
// only those rows after it.
// ---------------------------------------------------------------------------
__global__ __launch_bounds__(512, 1)
void attn_kernel(const bf16* Q, const bf16* __restrict__ Kb,
                 const bf16* __restrict__ Vt, bf16* AO) {
  __shared__ __align__(16) float Ebuf[32 * 260];     // [q][h*32+k], 33.3 KB
  __shared__ __align__(16) bf16  Pbuf[8 * 32 * 40];  // [h][q][k pad 40], 20 KB

  const int tid  = threadIdx.x;
  const int h    = tid >> 6;
  const int lane = tid & 63;
  const int l15  = lane & 15;
  const int q4   = lane >> 4;
  const int b    = blockIdx.x >> 6;
  const int qt   = blockIdx.x & 63;
  const int qrow0 = b * 2048 + qt * 32;

  // Persistent Q fragments: 2 q-16tiles x 3 d-chunks.
  bf16x8 aq[2][3];
#pragma unroll
  for (int i = 0; i < 2; i++)
#pragma unroll
    for (int c = 0; c < 3; c++)
      aq[i][c] = *(const bf16x8*)
          &Q[(size_t)(qrow0 + i * 16 + l15) * 768 + h * 96 + c * 32 + q4 * 8];

  fx4 o[2][6];
#pragma unroll
  for (int i = 0; i < 2; i++)
#pragma unroll
    for (int j = 0; j < 6; j++) o[i][j] = (fx4){0.f, 0.f, 0.f, 0.f};

  // Per-lane fixed base pointers.
  const bf16* Kp0 = Kb + (size_t)(b * 2048 + l15) * 768 + h * 96 + q4 * 8;
  const bf16* Vp0 = Vt + (size_t)((b * 8 + h) * 96 + l15) * 2048 + q4 * 8;

  // Double-buffered K/V fragment registers.
  bf16x8 bkA[2][3], bvA[6], bkB[2][3], bvB[6];

  auto loadKV = [&](int kt, bf16x8 (&bk)[2][3], bf16x8 (&bv)[6]) {
    const bf16* Kp = Kp0 + (size_t)(kt * 32) * 768;
#pragma unroll
    for (int j = 0; j < 2; j++)
#pragma unroll
      for (int c = 0; c < 3; c++)
        bk[j][c] = *(const bf16x8*)(Kp + (size_t)(j * 16) * 768 + c * 32);
#pragma unroll
    for (int j2 = 0; j2 < 6; j2++)
      bv[j2] = *(const bf16x8*)(Vp0 + (size_t)(j2 * 16) * 2048 + kt * 32);
  };

  auto body = [&](int kt, bf16x8 (&bk)[2][3], bf16x8 (&bv)[6],
                  bf16x8 (&nk)[2][3], bf16x8 (&nv)[6]) {
    // Prefetch NEXT iteration's fragments (stay in flight across the whole
    // body now that barriers don't drain vmcnt and regs aren't capped).
    const int kn = (kt + 1 < 64) ? kt + 1 : 63;
    loadKV(kn, nk, nv);

    // E = Q K^T : [32q x 32k] for this head (current regs, loaded last iter).
    fx4 e[2][2];
    e[0][0] = e[0][1] = e[1][0] = e[1][1] = (fx4){0.f, 0.f, 0.f, 0.f};
#pragma unroll
    for (int c = 0; c < 3; c++)
#pragma unroll
      for (int j = 0; j < 2; j++) {
        e[0][j] = MFMA16(aq[0][c], bk[j][c], e[0][j]);
        e[1][j] = MFMA16(aq[1][c], bk[j][c], e[1][j]);
      }

    // Scatter E -> Ebuf[q*260 + h*32 + k]
#pragma unroll
    for (int i = 0; i < 2; i++)
#pragma unroll
      for (int j = 0; j < 2; j++)
#pragma unroll
        for (int r = 0; r < 4; r++)
          Ebuf[(i * 16 + q4 * 4 + r) * 260 + h * 32 + j * 16 + l15] =
              e[i][j][r];
    barrier_nodrain();

    // Softmax over heads. 1024 (q,k) pairs, 2 per thread.
#pragma unroll
    for (int pp = 0; pp < 2; pp++) {
      const int p = tid + pp * 512;
      const int q = p >> 5, k = p & 31;
      float v[8];
#pragma unroll
      for (int hh = 0; hh < 8; hh++) v[hh] = Ebuf[q * 260 + hh * 32 + k];
      float m = v[0];
#pragma unroll
      for (int hh = 1; hh < 8; hh++) m = fmaxf(m, v[hh]);
      float sm = 0.f;
#pragma unroll
      for (int hh = 0; hh < 8; hh++) { v[hh] = __expf(v[hh] - m); sm += v[hh]; }
      const float inv = 1.0f / (sm * 27.712812921102035f);  // / sqrt(768)
#pragma unroll
      for (int hh = 0; hh < 8; hh++)
        Pbuf[hh * 1280 + q * 40 + k] = (bf16)(v[hh] * inv);
    }
    barrier_nodrain();

    // O += P @ V (V regs from the previous iteration's prefetch).
    bf16x8 ap[2];
#pragma unroll
    for (int i = 0; i < 2; i++)
      ap[i] = *(const bf16x8*)&Pbuf[h * 1280 + (i * 16 + l15) * 40 + q4 * 8];
#pragma unroll
    for (int j2 = 0; j2 < 6; j2++) {
      o[0][j2] = MFMA16(ap[0], bv[j2], o[0][j2]);
      o[1][j2] = MFMA16(ap[1], bv[j2], o[1][j2]);
    }
  };

  loadKV(0, bkA, bvA);
  for (int kt = 0; kt < 64; kt += 2) {
    body(kt,     bkA, bvA, bkB, bvB);
    body(kt + 1, bkB, bvB, bkA, bvA);
  }

  // Write AO[qrow0 + q][h*96 + d]
#pragma unroll
  for (int i = 0; i < 2; i++)
#pragma unroll
    for (int j2 = 0; j2 < 6; j2++)
#pragma unroll
      for (int r = 0; r < 4; r++)
        AO[(size_t)(qrow0 + i * 16 + q4 * 4 + r) * 768 + h * 96 + j2 * 16 + l15] =
            (bf16)(o[i][j2][r]);
}

// ---------------------------------------------------------------------------
// Memory plan (proven): d_out = xb + Kw (both dead before gemm_o overwrites
// d_out fp32). ws = Q + Vt (25.2 MB). AO aliases Q.
// ---------------------------------------------------------------------------
extern "C" void kernel_launch(void* const* d_in, const int* in_sizes, int n_in,
                              void* d_out, int out_size, void* d_ws,
                              size_t ws_size, hipStream_t stream) {
  const float* x  = (const float*)d_in[0];
  const float* Wq = (const float*)d_in[1];
  const float* bq = (const float*)d_in[2];
  const float* Wk = (const float*)d_in[3];
  const float* bk = (const float*)d_in[4];
  const float* Wv = (const float*)d_in[5];
  const float* bv = (const float*)d_in[6];
  const float* Wo = (const float*)d_in[7];
  const float* bo = (const float*)d_in[8];

  const size_t MN = (size_t)8192 * 768;
  bf16* xb = (bf16*)d_out;
  bf16* Kw = xb + MN;
  bf16* Q  = (bf16*)d_ws;
  bf16* Vt = Q + MN;
  bf16* AO = Q;  // aliases Q

  cvt_x_kernel<<<6144, 256, 0, stream>>>(x, xb);
  dim3 qkvgrid(18, 64);
  gemm_qkv<<<qkvgrid, 256, 0, stream>>>(xb, Wq, Wk, Wv, bq, bk, bv, Q, Kw, Vt);
  attn_kernel<<<256, 512, 0, stream>>>(Q, Kw, Vt, AO);
  dim3 ogrid(6, 64);
  gemm_o<<<ogrid, 256, 0, stream>>>(AO, Wo, bo, (float*)d_out);
}

// Round 5
// 319.239 us; speedup vs baseline: 2.2400x; 1.2238x over previous
//
#include <hip/hip_runtime.h>
#include <stdint.h>

typedef __bf16 bf16;
typedef __bf16 bf16x4 __attribute__((ext_vector_type(4)));
typedef __bf16 bf16x8 __attribute__((ext_vector_type(8)));
typedef float  fx4    __attribute__((ext_vector_type(4)));

#define MFMA16(a, b, c) __builtin_amdgcn_mfma_f32_16x16x32_bf16((a), (b), (c), 0, 0, 0)

// B=4, N=2048, E=768, H=8, D=96; M = B*N = 8192. User tensors fp32, out fp32.

// ---------------------------------------------------------------------------
// Barrier WITHOUT the vmem drain (lgkmcnt(0) only). Keeps global_load_lds
// DMA in flight across barriers. 0xC07F = vmcnt 63 (nowait), exp 7, lgkm 0.
// ---------------------------------------------------------------------------
__device__ __forceinline__ void barrier_nodrain() {
  __asm__ __volatile__("" ::: "memory");
  __builtin_amdgcn_s_waitcnt(0xC07F);
  __builtin_amdgcn_s_barrier();
  __asm__ __volatile__("" ::: "memory");
}

// Counted vmem wait: vmcnt(6) — wait oldest loads, allow 6 newest in flight.
__device__ __forceinline__ void wait_vm6() {
  __asm__ __volatile__("" ::: "memory");
  __builtin_amdgcn_s_waitcnt(0x0F76);
  __asm__ __volatile__("" ::: "memory");
}
// lgkmcnt(0) only (LDS reads retired; region safe to overwrite).
__device__ __forceinline__ void wait_lgkm0() {
  __asm__ __volatile__("" ::: "memory");
  __builtin_amdgcn_s_waitcnt(0xC07F);
  __asm__ __volatile__("" ::: "memory");
}

// DMA 16 B/lane global -> LDS (dest = wave-uniform base + lane*16, m104).
__device__ __forceinline__ void gload_lds16(const void* g, void* l) {
  __builtin_amdgcn_global_load_lds(
      (const __attribute__((address_space(1))) void*)g,
      (__attribute__((address_space(3))) void*)l, 16, 0, 0);
}

// ---------------------------------------------------------------------------
// x (fp32) -> bf16, 4 elems/thread.
// ---------------------------------------------------------------------------
__global__ __launch_bounds__(256)
void cvt_x_kernel(const float* __restrict__ x, bf16* __restrict__ xb) {
  const int i = (blockIdx.x * 256 + threadIdx.x) * 4;
  float4 v = *(const float4*)&x[i];
  bf16x4 o;
  o[0] = (bf16)v.x; o[1] = (bf16)v.y; o[2] = (bf16)v.z; o[3] = (bf16)v.w;
  *(bf16x4*)&xb[i] = o;
}

// ---------------------------------------------------------------------------
// Fused QKV GEMM. blockIdx.x: 0-5 Q, 6-11 K, 12-17 V. Tile 128x128, BK=32.
// R15: K and V are written in attention-staging tile layout (6144-B tiles
// per (b,h,kt)) so attn can DMA them into LDS linearly:
//   K: [b][h][kt][u=d/8][k32][d%8]   (frag-major for QK^T B-operand)
//   V: [b][h][kt][ku=k/8][d96][k%8]  (frag-major for PV  B-operand)
// Q unchanged (row-major [n][e]).
// ---------------------------------------------------------------------------
__global__ __launch_bounds__(256)
void gemm_qkv(const bf16* __restrict__ A,
              const float* __restrict__ Wq, const float* __restrict__ Wk,
              const float* __restrict__ Wv,
              const float* __restrict__ bq, const float* __restrict__ bk,
              const float* __restrict__ bv,
              bf16* __restrict__ Qo, bf16* __restrict__ Ka,
              bf16* __restrict__ Va) {
  constexpr int K = 768;
  __shared__ __align__(16) bf16 As[128 * 32];
  __shared__ __align__(16) bf16 Bs[128 * 32];

  const int tid  = threadIdx.x;
  const int wave = tid >> 6;
  const int lane = tid & 63;
  const int l15  = lane & 15;
  const int q4   = lane >> 4;
  const int wr   = wave >> 1;
  const int wc   = wave & 1;
  const int sel  = blockIdx.x / 6;
  const int cb0  = (blockIdx.x % 6) * 128;
  const int rb0  = blockIdx.y * 128;

  const float* W   = (sel == 0) ? Wq : (sel == 1) ? Wk : Wv;
  const float* bia = (sel == 0) ? bq : (sel == 1) ? bk : bv;

  fx4 acc[4][4];
#pragma unroll
  for (int i = 0; i < 4; i++)
#pragma unroll
    for (int j = 0; j < 4; j++) acc[i][j] = (fx4){0.f, 0.f, 0.f, 0.f};

  for (int k0 = 0; k0 < K; k0 += 32) {
    for (int c = tid; c < 512; c += 256) {
      const int row = c >> 2;
      const int kc  = (c & 3) << 3;
      *(uint4*)&As[row * 32 + kc] =
          *(const uint4*)&A[(size_t)(rb0 + row) * K + k0 + kc];
      const float* sb = W + (size_t)(cb0 + row) * K + k0 + kc;
      bf16x8 pb;
#pragma unroll
      for (int t = 0; t < 8; t++) pb[t] = (bf16)sb[t];
      *(bf16x8*)&Bs[row * 32 + kc] = pb;
    }
    __syncthreads();

    bf16x8 a[4], b[4];
#pragma unroll
    for (int i = 0; i < 4; i++)
      a[i] = *(const bf16x8*)&As[(wr * 64 + i * 16 + l15) * 32 + q4 * 8];
#pragma unroll
    for (int j = 0; j < 4; j++)
      b[j] = *(const bf16x8*)&Bs[(wc * 64 + j * 16 + l15) * 32 + q4 * 8];
#pragma unroll
    for (int i = 0; i < 4; i++)
#pragma unroll
      for (int j = 0; j < 4; j++)
        acc[i][j] = MFMA16(a[i], b[j], acc[i][j]);
    __syncthreads();
  }

  const int cb = cb0 + wc * 64;
  const int rb = rb0 + wr * 64;
#pragma unroll
  for (int j = 0; j < 4; j++) {
    const int o  = cb + j * 16 + l15;
    const float bj = bia[o];
    const int hh = o / 96;
    const int dd = o - hh * 96;
#pragma unroll
    for (int i = 0; i < 4; i++) {
      const int r0 = rb + i * 16 + q4 * 4;
      if (sel == 2) {
        // V tile: flat = tile*3072 + (k/8)*768 + d*8 + k%8 ; 4 consecutive k
        const int bb = r0 >> 11;
        const int n2 = r0 & 2047;
        const size_t flat =
            ((size_t)((bb * 8 + hh) * 64 + (n2 >> 5))) * 3072 +
            ((n2 >> 3) & 3) * 768 + dd * 8 + (n2 & 7);
        bf16x4 pk;
#pragma unroll
        for (int r = 0; r < 4; r++) pk[r] = (bf16)(acc[i][j][r] + bj);
        *(bf16x4*)&Va[flat] = pk;
      } else if (sel == 1) {
        // K tile: flat = tile*3072 + (d/8)*256 + k*8 + d%8
        const int u  = dd >> 3;
        const int de = dd & 7;
#pragma unroll
        for (int r = 0; r < 4; r++) {
          const int n  = r0 + r;
          const int bb = n >> 11;
          const int n2 = n & 2047;
          const size_t flat =
              ((size_t)((bb * 8 + hh) * 64 + (n2 >> 5))) * 3072 +
              u * 256 + (n2 & 31) * 8 + de;
          Ka[flat] = (bf16)(acc[i][j][r] + bj);
        }
      } else {
#pragma unroll
        for (int r = 0; r < 4; r++)
          Qo[(size_t)(r0 + r) * 768 + o] = (bf16)(acc[i][j][r] + bj);
      }
    }
  }
}

// ---------------------------------------------------------------------------
// Output projection: out[M,768] fp32 = AO bf16 @ Wo^T + bo (untouched).
// ---------------------------------------------------------------------------
__global__ __launch_bounds__(256)
void gemm_o(const bf16* __restrict__ A, const float* __restrict__ W,
            const float* __restrict__ bias, float* __restrict__ C) {
  constexpr int K = 768;
  __shared__ __align__(16) bf16 As[128 * 32];
  __shared__ __align__(16) bf16 Bs[128 * 32];

  const int tid  = threadIdx.x;
  const int wave = tid >> 6;
  const int lane = tid & 63;
  const int l15  = lane & 15;
  const int q4   = lane >> 4;
  const int wr   = wave >> 1;
  const int wc   = wave & 1;
  const int rb0  = blockIdx.y * 128;
  const int cb0  = blockIdx.x * 128;

  fx4 acc[4][4];
#pragma unroll
  for (int i = 0; i < 4; i++)
#pragma unroll
    for (int j = 0; j < 4; j++) acc[i][j] = (fx4){0.f, 0.f, 0.f, 0.f};

  for (int k0 = 0; k0 < K; k0 += 32) {
    for (int c = tid; c < 512; c += 256) {
      const int row = c >> 2;
      const int kc  = (c & 3) << 3;
      *(uint4*)&As[row * 32 + kc] =
          *(const uint4*)&A[(size_t)(rb0 + row) * K + k0 + kc];
      const float* sb = W + (size_t)(cb0 + row) * K + k0 + kc;
      bf16x8 pb;
#pragma unroll
      for (int t = 0; t < 8; t++) pb[t] = (bf16)sb[t];
      *(bf16x8*)&Bs[row * 32 + kc] = pb;
    }
    __syncthreads();

    bf16x8 a[4], b[4];
#pragma unroll
    for (int i = 0; i < 4; i++)
      a[i] = *(const bf16x8*)&As[(wr * 64 + i * 16 + l15) * 32 + q4 * 8];
#pragma unroll
    for (int j = 0; j < 4; j++)
      b[j] = *(const bf16x8*)&Bs[(wc * 64 + j * 16 + l15) * 32 + q4 * 8];
#pragma unroll
    for (int i = 0; i < 4; i++)
#pragma unroll
      for (int j = 0; j < 4; j++)
        acc[i][j] = MFMA16(a[i], b[j], acc[i][j]);
    __syncthreads();
  }

  const int cb = cb0 + wc * 64;
  const int rb = rb0 + wr * 64;
#pragma unroll
  for (int j = 0; j < 4; j++) {
    const int o  = cb + j * 16 + l15;
    const float bj = bias[o];
#pragma unroll
    for (int i = 0; i < 4; i++) {
      const int r0 = rb + i * 16 + q4 * 4;
#pragma unroll
      for (int r = 0; r < 4; r++)
        C[(size_t)(r0 + r) * 768 + o] = acc[i][j][r] + bj;
    }
  }
}

// ---------------------------------------------------------------------------
// Attention, softmax over HEADS (dim=1), / sqrt(768).
// R15: K/V staged via global_load_lds DMA into wave-private LDS regions.
//  - R10..R14 post-mortem: register K/V prefetch never materialized — the
//    compiler sinks the loads regardless of launch_bounds (VGPR stayed 108
//    at cap 256, R14). 24 serialized 16-B loads/body = ~6700 stall cyc.
//  - Fix: DMA needs ZERO dest VGPRs -> all 6 staging loads per tile issue
//    back-to-back and stay in flight across nodrain barriers. Counted
//    vmcnt(6) waits (never 0 mid-loop). Each DMA has a full body to land.
//  - Wave-private regions (wave=head) -> staging needs no barriers.
//  - K/V global layout = LDS layout (linear 6144-B tiles, see gemm_qkv),
//    satisfying the wave-uniform-linear DMA dest constraint; frag-major
//    order makes frag ds_read_b128 stride 16 B across lanes (2-way, free).
//  - Pbuf eliminated: softmax renormalizes Ebuf f32 IN PLACE (each (q,k)
//    thread owns its 8 h-slots); PV builds bf16 A-frags from Ebuf f32.
// LDS: Kbuf 48 KB + Vbuf 48 KB + Ebuf 32.5 KB = 131.5 KB (<160 KB; 1 blk/CU
// by LDS — fine, latency hidden by DMA pipeline, not occupancy).
// Schedule/body: vmcnt(6)[K ready] -> K frags -> lgkm0 -> DMA K(kt+1) ->
// QK^T -> scatter -> bar -> softmax(inplace) -> bar -> vmcnt(6)[V ready] ->
// V+P frags -> lgkm0 -> DMA V(kt+1) -> PV MFMA.
// AO aliases Q (reads own rows before loop, writes own rows after).
// ---------------------------------------------------------------------------
__global__ __launch_bounds__(512, 1)
void attn_kernel(const bf16* Q, const bf16* __restrict__ Ka,
                 const bf16* __restrict__ Va, bf16* AO) {
  __shared__ __align__(16) bf16  Kbuf[8 * 3072];   // [h][u12][k32][8] 48 KB
  __shared__ __align__(16) bf16  Vbuf[8 * 3072];   // [h][ku4][d96][8] 48 KB
  __shared__ __align__(16) float Ebuf[32 * 260];   // [q][h*32+k]    32.5 KB

  const int tid  = threadIdx.x;
  const int h    = tid >> 6;
  const int lane = tid & 63;
  const int l15  = lane & 15;
  const int q4   = lane >> 4;
  const int b    = blockIdx.x >> 6;
  const int qt   = blockIdx.x & 63;
  const int qrow0 = b * 2048 + qt * 32;

  // Persistent Q fragments: 2 q-16tiles x 3 d-chunks.
  bf16x8 aq[2][3];
#pragma unroll
  for (int i = 0; i < 2; i++)
#pragma unroll
    for (int c = 0; c < 3; c++)
      aq[i][c] = *(const bf16x8*)
          &Q[(size_t)(qrow0 + i * 16 + l15) * 768 + h * 96 + c * 32 + q4 * 8];

  fx4 o[2][6];
#pragma unroll
  for (int i = 0; i < 2; i++)
#pragma unroll
    for (int j = 0; j < 6; j++) o[i][j] = (fx4){0.f, 0.f, 0.f, 0.f};

  // Per-head global tile bases (tiles of 3072 elems = 6144 B, [b][h][kt]).
  const bf16* Kt0 = Ka + (size_t)(b * 8 + h) * 64 * 3072;
  const bf16* Vt0 = Va + (size_t)(b * 8 + h) * 64 * 3072;
  bf16* Kl = &Kbuf[h * 3072];
  bf16* Vl = &Vbuf[h * 3072];

  auto stageK = [&](int kt) {
    const bf16* src = Kt0 + (size_t)kt * 3072 + lane * 8;
#pragma unroll
    for (int t = 0; t < 6; t++)
      gload_lds16(src + t * 512, Kl + t * 512);
  };
  auto stageV = [&](int kt) {
    const bf16* src = Vt0 + (size_t)kt * 3072 + lane * 8;
#pragma unroll
    for (int t = 0; t < 6; t++)
      gload_lds16(src + t * 512, Vl + t * 512);
  };

  stageK(0);
  stageV(0);

  for (int kt = 0; kt < 64; kt++) {
    const int kn = (kt + 1 < 64) ? kt + 1 : 63;

    // --- K(kt) ready? (allow V(kt)'s 6 loads outstanding) ---
    wait_vm6();

    // K frags: lane(l15,q4): k=j*16+l15, d-unit=(c*4+q4) -> 16 B, 2-way.
    bf16x8 bk[2][3];
#pragma unroll
    for (int j = 0; j < 2; j++)
#pragma unroll
      for (int c = 0; c < 3; c++)
        bk[j][c] =
            *(const bf16x8*)&Kl[(c * 4 + q4) * 256 + (j * 16 + l15) * 8];

    // K region free once reads retire; DMA next K tile (lands during
    // softmax/PV + next body's start).
    wait_lgkm0();
    stageK(kn);

    // E = Q K^T : [32q x 32k] for this head.
    fx4 e[2][2];
    e[0][0] = e[0][1] = e[1][0] = e[1][1] = (fx4){0.f, 0.f, 0.f, 0.f};
#pragma unroll
    for (int c = 0; c < 3; c++)
#pragma unroll
      for (int j = 0; j < 2; j++) {
        e[0][j] = MFMA16(aq[0][c], bk[j][c], e[0][j]);
        e[1][j] = MFMA16(aq[1][c], bk[j][c], e[1][j]);
      }

    // Scatter E -> Ebuf[q*260 + h*32 + k]
#pragma unroll
    for (int i = 0; i < 2; i++)
#pragma unroll
      for (int j = 0; j < 2; j++)
#pragma unroll
        for (int r = 0; r < 4; r++)
          Ebuf[(i * 16 + q4 * 4 + r) * 260 + h * 32 + j * 16 + l15] =
              e[i][j][r];
    barrier_nodrain();

    // Softmax over heads, IN PLACE (f32). 1024 (q,k) pairs, 2 per thread.
#pragma unroll
    for (int pp = 0; pp < 2; pp++) {
      const int p = tid + pp * 512;
      const int q = p >> 5, k = p & 31;
      float* row = &Ebuf[q * 260 + k];
      float v[8];
#pragma unroll
      for (int hh = 0; hh < 8; hh++) v[hh] = row[hh * 32];
      float m = v[0];
#pragma unroll
      for (int hh = 1; hh < 8; hh++) m = fmaxf(m, v[hh]);
      float sm = 0.f;
#pragma unroll
      for (int hh = 0; hh < 8; hh++) { v[hh] = __expf(v[hh] - m); sm += v[hh]; }
      const float inv = 1.0f / (sm * 27.712812921102035f);  // / sqrt(768)
#pragma unroll
      for (int hh = 0; hh < 8; hh++) row[hh * 32] = v[hh] * inv;
    }
    barrier_nodrain();

    // --- V(kt) ready? (allow K(kn)'s 6 loads outstanding) ---
    wait_vm6();

    // V frags: lane(l15,q4): d=j2*16+l15, k-unit=q4 -> 16 B, 2-way.
    bf16x8 bv[6];
#pragma unroll
    for (int j2 = 0; j2 < 6; j2++)
      bv[j2] = *(const bf16x8*)&Vl[q4 * 768 + (j2 * 16 + l15) * 8];

    // P frags from Ebuf f32 -> bf16.
    bf16x8 ap[2];
#pragma unroll
    for (int i = 0; i < 2; i++) {
      const float* ps = &Ebuf[(i * 16 + l15) * 260 + h * 32 + q4 * 8];
      fx4 p0 = *(const fx4*)ps;
      fx4 p1 = *(const fx4*)(ps + 4);
      bf16x8 t;
      t[0] = (bf16)p0[0]; t[1] = (bf16)p0[1];
      t[2] = (bf16)p0[2]; t[3] = (bf16)p0[3];
      t[4] = (bf16)p1[0]; t[5] = (bf16)p1[1];
      t[6] = (bf16)p1[2]; t[7] = (bf16)p1[3];
      ap[i] = t;
    }

    // V region free; DMA next V tile.
    wait_lgkm0();
    stageV(kn);

    // O += P @ V.
#pragma unroll
    for (int j2 = 0; j2 < 6; j2++) {
      o[0][j2] = MFMA16(ap[0], bv[j2], o[0][j2]);
      o[1][j2] = MFMA16(ap[1], bv[j2], o[1][j2]);
    }
  }

  // Drain outstanding DMA before exit/stores.
  __builtin_amdgcn_s_waitcnt(0x0070);

  // Write AO[qrow0 + q][h*96 + d]
#pragma unroll
  for (int i = 0; i < 2; i++)
#pragma unroll
    for (int j2 = 0; j2 < 6; j2++)
#pragma unroll
      for (int r = 0; r < 4; r++)
        AO[(size_t)(qrow0 + i * 16 + q4 * 4 + r) * 768 + h * 96 + j2 * 16 + l15] =
            (bf16)(o[i][j2][r]);
}

// ---------------------------------------------------------------------------
// Memory plan: d_out = xb + Ka (both dead before gemm_o overwrites d_out).
// ws = Q + Va (25.2 MB, same footprint as before). AO aliases Q.
// K_attn/V_attn are exactly MN elems each (4*8*64*3072 = 8192*768).
// ---------------------------------------------------------------------------
extern "C" void kernel_launch(void* const* d_in, const int* in_sizes, int n_in,
                              void* d_out, int out_size, void* d_ws,
                              size_t ws_size, hipStream_t stream) {
  const float* x  = (const float*)d_in[0];
  const float* Wq = (const float*)d_in[1];
  const float* bq = (const float*)d_in[2];
  const float* Wk = (const float*)d_in[3];
  const float* bk = (const float*)d_in[4];
  const float* Wv = (const float*)d_in[5];
  const float* bv = (const float*)d_in[6];
  const float* Wo = (const float*)d_in[7];
  const float* bo = (const float*)d_in[8];

  const size_t MN = (size_t)8192 * 768;
  bf16* xb = (bf16*)d_out;
  bf16* Ka = xb + MN;
  bf16* Q  = (bf16*)d_ws;
  bf16* Va = Q + MN;
  bf16* AO = Q;  // aliases Q

  cvt_x_kernel<<<6144, 256, 0, stream>>>(x, xb);
  dim3 qkvgrid(18, 64);
  gemm_qkv<<<qkvgrid, 256, 0, stream>>>(xb, Wq, Wk, Wv, bq, bk, bv, Q, Ka, Va);
  attn_kernel<<<256, 512, 0, stream>>>(Q, Ka, Va, AO);
  dim3 ogrid(6, 64);
  gemm_o<<<ogrid, 256, 0, stream>>>(AO, Wo, bo, (float*)d_out);
}